// Round 1
// 642.053 us; speedup vs baseline: 1.0601x; 1.0601x over previous
//
#include <hip/hip_runtime.h>

typedef __bf16 bf16;
typedef __bf16 bf16x4 __attribute__((ext_vector_type(4)));
typedef __bf16 bf16x8 __attribute__((ext_vector_type(8)));
typedef float f32x4 __attribute__((ext_vector_type(4)));
typedef float floatx4 __attribute__((ext_vector_type(4)));

#define S 96
#define DIN 768
#define DOUT 256
#define MROWS 73728  // 8*96*96

__device__ static inline void async16(const bf16* g, bf16* l) {
    __builtin_amdgcn_global_load_lds(
        (const __attribute__((address_space(1))) void*)g,
        (__attribute__((address_space(3))) void*)l,
        16, 0, 0);
}

// ---------------------------------------------------------------------------
// gether1: X = gether(H) + H  (coefficient 2 on center row). fp32 in, bf16 out
// grid (8*S, 2): block handles 48 k-rows of one (b,l)
// XCD swizzle: each XCD owns a contiguous (b,l) range so the up/down neighbor
// rows (blocks x±1) are L2-resident instead of re-fetched from HBM.
// ---------------------------------------------------------------------------
__global__ __launch_bounds__(256) void k_gether1(
    const float* __restrict__ H, const float* __restrict__ Asim,
    const float* __restrict__ Tsim, const float* __restrict__ Adj,
    bf16* __restrict__ X)
{
    __shared__ float adjs[S];
    __shared__ float ts[S];
    __shared__ float diagf[DIN];
    int bx = blockIdx.x;
    bx = (bx & 7) * (gridDim.x >> 3) + (bx >> 3);  // 768 % 8 == 0: bijective
    int b = bx / S, l = bx % S;
    int tid = threadIdx.x;
    long row0 = (long)(b * S + l) * S;
    if (tid < S) {
        adjs[tid] = Adj[(b * S + l) * S + tid];
        ts[tid]   = Tsim[b * S + tid];
    }
    for (int i = tid; i < DIN / 4; i += 256)
        *(f32x4*)&diagf[i * 4] = *(const f32x4*)&H[(row0 + l) * DIN + i * 4];
    float a_up = (l > 0)     ? Asim[b * S + l - 1] : 0.f;
    float a_dn = (l < S - 1) ? Asim[b * S + l + 1] : 0.f;
    long du = (l > 0)     ? -(long)S * DIN : 0;
    long dd = (l < S - 1) ?  (long)S * DIN : 0;
    __syncthreads();

    int lane = tid & 63, wv = tid >> 6;
    int k0 = blockIdx.y * (S / 2);
    for (int k = k0 + wv; k < k0 + S / 2; k += 4) {
        float tl = (k > 0)     ? ts[k - 1] : 0.f;
        float tr = (k < S - 1) ? ts[k + 1] : 0.f;
        long  dl = (k > 0)     ? -(long)DIN : 0;
        long  dr = (k < S - 1) ?  (long)DIN : 0;
        float aj = adjs[k];
        const float* hrow = H + (row0 + k) * DIN;
        bf16* xrow = X + (row0 + k) * DIN;
#pragma unroll
        for (int c = 0; c < 3; ++c) {
            int col = (lane + c * 64) * 4;
            const float* hc = hrow + col;
            f32x4 vc = *(const f32x4*)hc;
            f32x4 vl = *(const f32x4*)(hc + dl);
            f32x4 vr = *(const f32x4*)(hc + dr);
            f32x4 vu = *(const f32x4*)(hc + du);
            f32x4 vd = *(const f32x4*)(hc + dd);
            bf16x4 o;
#pragma unroll
            for (int j = 0; j < 4; ++j) {
                float v = 2.f * vc[j] + aj * diagf[col + j]
                        + tl * vl[j] + tr * vr[j]
                        + a_up * vu[j] + a_dn * vd[j];
                o[j] = (bf16)v;
            }
            *(bf16x4*)&xrow[col] = o;
        }
    }
}

// ---------------------------------------------------------------------------
// gether2: sources are h1 = relu(g1 * y * invr) reconstructed on the fly.
// grid (8*S, 2); same XCD swizzle as gether1.
// ---------------------------------------------------------------------------
__global__ __launch_bounds__(256) void k_gether2(
    const bf16* __restrict__ Y, const float* __restrict__ INV,
    const float* __restrict__ G1, const float* __restrict__ Asim,
    const float* __restrict__ Tsim, const float* __restrict__ Adj,
    bf16* __restrict__ X)
{
    __shared__ float adjs[S];
    __shared__ float ts[S];
    __shared__ float diagf[DIN];
    __shared__ float g1s[DIN];
    int bx = blockIdx.x;
    bx = (bx & 7) * (gridDim.x >> 3) + (bx >> 3);
    int b = bx / S, l = bx % S;
    int tid = threadIdx.x;
    long row0 = (long)(b * S + l) * S;
    for (int i = tid; i < DIN; i += 256) g1s[i] = G1[i];
    __syncthreads();
    if (tid < S) {
        adjs[tid] = Adj[(b * S + l) * S + tid];
        ts[tid]   = Tsim[b * S + tid];
        float iv = INV[row0 + l];
        bf16x8 yv = *(const bf16x8*)&Y[(row0 + l) * DIN + tid * 8];
#pragma unroll
        for (int j = 0; j < 8; ++j) {
            float v = g1s[tid * 8 + j] * (float)yv[j] * iv;
            diagf[tid * 8 + j] = v > 0.f ? v : 0.f;
        }
    }
    float a_up = (l > 0)     ? Asim[b * S + l - 1] : 0.f;
    float a_dn = (l < S - 1) ? Asim[b * S + l + 1] : 0.f;
    long du = (l > 0)     ? -(long)S * DIN : 0;
    long dd = (l < S - 1) ?  (long)S * DIN : 0;
    int ou = (l > 0) ? -S : 0;
    int od = (l < S - 1) ? S : 0;
    __syncthreads();

    int lane = tid & 63, wv = tid >> 6;
    int k0 = blockIdx.y * (S / 2);
    for (int k = k0 + wv; k < k0 + S / 2; k += 4) {
        float tl = (k > 0)     ? ts[k - 1] : 0.f;
        float tr = (k < S - 1) ? ts[k + 1] : 0.f;
        int   ol = (k > 0)     ? -1 : 0;
        int   orr = (k < S - 1) ? 1 : 0;
        float aj = adjs[k];
        float ivc = INV[row0 + k];
        float ivl = INV[row0 + k + ol];
        float ivr = INV[row0 + k + orr];
        float ivu = INV[row0 + k + ou];
        float ivd = INV[row0 + k + od];
        const bf16* yrow = Y + (row0 + k) * DIN;
        bf16* xrow = X + (row0 + k) * DIN;
#pragma unroll
        for (int c = 0; c < 3; ++c) {
            int col = (lane + c * 64) * 4;
            const bf16* yc = yrow + col;
            bf16x4 vc = *(const bf16x4*)yc;
            bf16x4 vl = *(const bf16x4*)(yc + (long)ol * DIN);
            bf16x4 vr = *(const bf16x4*)(yc + (long)orr * DIN);
            bf16x4 vu = *(const bf16x4*)(yc + du);
            bf16x4 vd = *(const bf16x4*)(yc + dd);
            bf16x4 o;
#pragma unroll
            for (int j = 0; j < 4; ++j) {
                float g = g1s[col + j];
                float hc_ = g * (float)vc[j] * ivc; hc_ = hc_ > 0.f ? hc_ : 0.f;
                float hl_ = g * (float)vl[j] * ivl; hl_ = hl_ > 0.f ? hl_ : 0.f;
                float hr_ = g * (float)vr[j] * ivr; hr_ = hr_ > 0.f ? hr_ : 0.f;
                float hu_ = g * (float)vu[j] * ivu; hu_ = hu_ > 0.f ? hu_ : 0.f;
                float hd_ = g * (float)vd[j] * ivd; hd_ = hd_ > 0.f ? hd_ : 0.f;
                float v = 2.f * hc_ + aj * diagf[col + j]
                        + tl * hl_ + tr * hr_ + a_up * hu_ + a_dn * hd_;
                o[j] = (bf16)v;
            }
            *(bf16x4*)&xrow[col] = o;
        }
    }
}

// ---------------------------------------------------------------------------
// GEMM1: Y1[M x 768] = X @ W1T^T + b1 (bf16), ssq atomics.
// 128x128 tile + XOR swizzle (0 bank conflicts) as before, NOW with:
//  - 2-phase double-buffered LDS (T3 minimum recipe): stage tile t+1 BEFORE
//    ds_read/MFMA of tile t; single __syncthreads (vmcnt0+lgkm0+barrier) per
//    K-step. Load latency hides under ~1900cy of MFMA instead of serializing.
//  - XCD-bijective swizzle (grid 3456 = 8*432): each XCD owns contiguous row
//    panels, iterates the 6 col tiles within, so X panels are L2-hits after
//    the first fetch (was fetched ~3x: FETCH 345MB vs 125MB ideal).
// ---------------------------------------------------------------------------
__global__ __launch_bounds__(256) void k_gemm1(
    const bf16* __restrict__ Xm, const bf16* __restrict__ WT,
    const float* __restrict__ bias, bf16* __restrict__ Y,
    float* __restrict__ ssq)
{
    constexpr int K = 768, N = 768;
    __shared__ __align__(16) bf16 As[2][128 * 32];
    __shared__ __align__(16) bf16 Bs[2][128 * 32];
    int t = threadIdx.x;
    int wg = blockIdx.x;
    wg = (wg & 7) * (gridDim.x >> 3) + (wg >> 3);  // 3456 % 8 == 0: bijective
    int colBase = (wg % 6) * 128;                  // col fastest within XCD
    int rowBase = (wg / 6) * 128;
    int lane = t & 63, w = t >> 6;
    int quad = lane >> 4, l16 = lane & 15;
    int wr = w >> 1, wc = w & 1;

    floatx4 acc[4][4];
#pragma unroll
    for (int i = 0; i < 4; ++i)
#pragma unroll
        for (int j = 0; j < 4; ++j) acc[i][j] = (floatx4)0.f;

    int chunk = (t & 3) ^ ((t >> 3) & 3);
    const bf16* gA = Xm + (size_t)(rowBase + (t >> 2)) * K + chunk * 8;
    const bf16* gB = WT + (size_t)(colBase + (t >> 2)) * K + chunk * 8;
    int l8 = t * 8;

    auto stage = [&](int buf, int kk) {
        async16(gA + kk, &As[buf][l8]);
        async16(gA + kk + 64 * K, &As[buf][l8 + 2048]);
        async16(gB + kk, &Bs[buf][l8]);
        async16(gB + kk + 64 * K, &Bs[buf][l8 + 2048]);
    };

    stage(0, 0);
    __syncthreads();
    int cur = 0;
    for (int kk = 0; kk < K; kk += 32) {
        if (kk + 32 < K) stage(cur ^ 1, kk + 32);
        bf16x8 af[4], bfr[4];
#pragma unroll
        for (int i = 0; i < 4; ++i) {
            int ra = wr * 64 + i * 16 + l16;
            af[i] = *(const bf16x8*)&As[cur][ra * 32 + (quad ^ ((ra >> 1) & 3)) * 8];
        }
#pragma unroll
        for (int j = 0; j < 4; ++j) {
            int rb = wc * 64 + j * 16 + l16;
            bfr[j] = *(const bf16x8*)&Bs[cur][rb * 32 + (quad ^ ((rb >> 1) & 3)) * 8];
        }
#pragma unroll
        for (int i = 0; i < 4; ++i)
#pragma unroll
            for (int j = 0; j < 4; ++j)
                acc[i][j] = __builtin_amdgcn_mfma_f32_16x16x32_bf16(
                    af[i], bfr[j], acc[i][j], 0, 0, 0);
        __syncthreads();   // drains next-tile loads (issued ~1900cy ago)
        cur ^= 1;
    }

    float bv[4];
#pragma unroll
    for (int j = 0; j < 4; ++j)
        bv[j] = bias[colBase + wc * 64 + j * 16 + l16];
#pragma unroll
    for (int i = 0; i < 4; ++i) {
#pragma unroll
        for (int r = 0; r < 4; ++r) {
            int row = rowBase + wr * 64 + i * 16 + quad * 4 + r;
            bf16* yp = Y + (size_t)row * N + colBase + wc * 64 + l16;
            float s = 0.f;
#pragma unroll
            for (int j = 0; j < 4; ++j) {
                float v = acc[i][j][r] + bv[j];
                s += v * v;
                yp[j * 16] = (bf16)v;
            }
            s += __shfl_xor(s, 1);
            s += __shfl_xor(s, 2);
            s += __shfl_xor(s, 4);
            s += __shfl_xor(s, 8);
            if (l16 == 0) atomicAdd(&ssq[row], s);
        }
    }
}

// ---------------------------------------------------------------------------
// GEMM2 fused: out[M x 256] = relu(g2 * t5norm(X2 @ W2T^T + b2)) directly.
// Block covers 128 rows x ALL 256 cols: 4 waves 2x2, each 64x128 (4x8 frags).
// Row-ssq reduced in-block via LDS; no global ssq, no second pass, no Y2.
// Same 2-phase double-buffer upgrade as k_gemm1 (LDS 49KB, 2 blk/CU OK).
// ---------------------------------------------------------------------------
__global__ __launch_bounds__(256, 2) void k_gemm2f(
    const bf16* __restrict__ Xm, const bf16* __restrict__ WT,
    const float* __restrict__ bias, const float* __restrict__ G2,
    float* __restrict__ out)
{
    constexpr int K = 768, N = 256;
    __shared__ __align__(16) bf16 As[2][128 * 32];
    __shared__ __align__(16) bf16 Bs[2][256 * 32];
    __shared__ float ssqs[2][128];
    int t = threadIdx.x;
    int rowBase = blockIdx.x * 128;
    int lane = t & 63, w = t >> 6;
    int quad = lane >> 4, l16 = lane & 15;
    int wr = w >> 1, wc = w & 1;

    floatx4 acc[4][8];
#pragma unroll
    for (int i = 0; i < 4; ++i)
#pragma unroll
        for (int j = 0; j < 8; ++j) acc[i][j] = (floatx4)0.f;

    int chunk = (t & 3) ^ ((t >> 3) & 3);
    const bf16* gA = Xm + (size_t)(rowBase + (t >> 2)) * K + chunk * 8;
    const bf16* gB = WT + (size_t)(t >> 2) * K + chunk * 8;
    int l8 = t * 8;

    auto stage = [&](int buf, int kk) {
        async16(gA + kk, &As[buf][l8]);
        async16(gA + kk + 64 * K, &As[buf][l8 + 2048]);
        async16(gB + kk, &Bs[buf][l8]);
        async16(gB + kk + 64 * K, &Bs[buf][l8 + 2048]);
        async16(gB + kk + 128 * K, &Bs[buf][l8 + 4096]);
        async16(gB + kk + 192 * K, &Bs[buf][l8 + 6144]);
    };

    stage(0, 0);
    __syncthreads();
    int cur = 0;
    for (int kk = 0; kk < K; kk += 32) {
        if (kk + 32 < K) stage(cur ^ 1, kk + 32);
        bf16x8 af[4], bfr[8];
#pragma unroll
        for (int i = 0; i < 4; ++i) {
            int ra = wr * 64 + i * 16 + l16;
            af[i] = *(const bf16x8*)&As[cur][ra * 32 + (quad ^ ((ra >> 1) & 3)) * 8];
        }
#pragma unroll
        for (int j = 0; j < 8; ++j) {
            int rb = wc * 128 + j * 16 + l16;
            bfr[j] = *(const bf16x8*)&Bs[cur][rb * 32 + (quad ^ ((rb >> 1) & 3)) * 8];
        }
#pragma unroll
        for (int i = 0; i < 4; ++i)
#pragma unroll
            for (int j = 0; j < 8; ++j)
                acc[i][j] = __builtin_amdgcn_mfma_f32_16x16x32_bf16(
                    af[i], bfr[j], acc[i][j], 0, 0, 0);
        __syncthreads();
        cur ^= 1;
    }

    float bv[8], gv[8];
#pragma unroll
    for (int j = 0; j < 8; ++j) {
        int col = wc * 128 + j * 16 + l16;
        bv[j] = bias[col];
        gv[j] = G2[col];
    }
    // per-row sum of squares -> LDS (each (wc, local row) slot written once)
#pragma unroll
    for (int i = 0; i < 4; ++i) {
#pragma unroll
        for (int r = 0; r < 4; ++r) {
            float s = 0.f;
#pragma unroll
            for (int j = 0; j < 8; ++j) {
                float v = acc[i][j][r] + bv[j];
                s += v * v;
            }
            s += __shfl_xor(s, 1);
            s += __shfl_xor(s, 2);
            s += __shfl_xor(s, 4);
            s += __shfl_xor(s, 8);
            if (l16 == 0)
                ssqs[wc][wr * 64 + i * 16 + quad * 4 + r] = s;
        }
    }
    __syncthreads();
#pragma unroll
    for (int i = 0; i < 4; ++i) {
#pragma unroll
        for (int r = 0; r < 4; ++r) {
            int lr = wr * 64 + i * 16 + quad * 4 + r;
            float inv = rsqrtf((ssqs[0][lr] + ssqs[1][lr]) * (1.f / N) + 1e-12f);
            float* op = out + (size_t)(rowBase + lr) * N + wc * 128 + l16;
#pragma unroll
            for (int j = 0; j < 8; ++j) {
                float v = (acc[i][j][r] + bv[j]) * gv[j] * inv;
                op[j * 16] = v > 0.f ? v : 0.f;
            }
        }
    }
}

// ---------------------------------------------------------------------------
__global__ __launch_bounds__(256) void k_invr(float* ssq, int n, float invD)
{
    int i = blockIdx.x * 256 + threadIdx.x;
    if (i < n) ssq[i] = rsqrtf(ssq[i] * invD + 1e-12f);
}

// tiled transpose + cast: in fp32 [R][C] -> out bf16 [C][R]; grid (C/32, R/32)
__global__ __launch_bounds__(256) void k_castT(
    const float* __restrict__ in, bf16* __restrict__ out, int R, int C)
{
    __shared__ float tile[32][33];
    int lx = threadIdx.x & 31, ly = threadIdx.x >> 5;
    int c0 = blockIdx.x * 32, r0 = blockIdx.y * 32;
#pragma unroll
    for (int k = 0; k < 4; ++k)
        tile[ly + 8 * k][lx] = in[(size_t)(r0 + ly + 8 * k) * C + c0 + lx];
    __syncthreads();
#pragma unroll
    for (int k = 0; k < 4; ++k)
        out[(size_t)(c0 + ly + 8 * k) * R + r0 + lx] = (bf16)tile[lx][ly + 8 * k];
}

// ---------------------------------------------------------------------------
extern "C" void kernel_launch(void* const* d_in, const int* in_sizes, int n_in,
                              void* d_out, int out_size, void* d_ws, size_t ws_size,
                              hipStream_t stream)
{
    const float* table = (const float*)d_in[0];
    const float* asim  = (const float*)d_in[1];
    const float* tsim  = (const float*)d_in[2];
    const float* adj   = (const float*)d_in[3];
    const float* W1    = (const float*)d_in[4];
    const float* b1    = (const float*)d_in[5];
    const float* g1    = (const float*)d_in[6];
    const float* W2    = (const float*)d_in[7];
    const float* b2    = (const float*)d_in[8];
    const float* g2    = (const float*)d_in[9];
    float* out = (float*)d_out;

    char* ws = (char*)d_ws;
    const size_t SZ_X = (size_t)MROWS * DIN * 2;          // 113246208 bytes
    bf16*  X    = (bf16*)ws;                               // [M,768] bf16
    bf16*  Y1   = (bf16*)(ws + SZ_X);                      // [M,768] bf16
    bf16*  W1T  = (bf16*)(ws + 2 * SZ_X);
    bf16*  W2T  = (bf16*)(ws + 2 * SZ_X + 1179648);
    float* ssq1 = (float*)(ws + 2 * SZ_X + 1179648 + 393216);

    hipMemsetAsync(ssq1, 0, (size_t)MROWS * 4, stream);
    k_castT<<<dim3(DIN / 32, DIN / 32), 256, 0, stream>>>(W1, W1T, DIN, DIN);
    k_castT<<<dim3(DOUT / 32, DIN / 32), 256, 0, stream>>>(W2, W2T, DIN, DOUT);

    k_gether1<<<dim3(8 * S, 2), 256, 0, stream>>>(table, asim, tsim, adj, X);
    k_gemm1<<<dim3((DIN / 128) * (MROWS / 128)), 256, 0, stream>>>(X, W1T, b1, Y1, ssq1);
    k_invr<<<MROWS / 256, 256, 0, stream>>>(ssq1, MROWS, 1.f / DIN);
    k_gether2<<<dim3(8 * S, 2), 256, 0, stream>>>(Y1, ssq1, g1, asim, tsim, adj, X);
    k_gemm2f<<<MROWS / 128, 256, 0, stream>>>(X, W2T, b2, g2, out);
}

// Round 2
// 636.011 us; speedup vs baseline: 1.0702x; 1.0095x over previous
//
#include <hip/hip_runtime.h>

typedef __bf16 bf16;
typedef __bf16 bf16x4 __attribute__((ext_vector_type(4)));
typedef __bf16 bf16x8 __attribute__((ext_vector_type(8)));
typedef float f32x4 __attribute__((ext_vector_type(4)));
typedef float floatx4 __attribute__((ext_vector_type(4)));

#define S 96
#define DIN 768
#define DOUT 256
#define MROWS 73728  // 8*96*96

__device__ static inline void async16(const bf16* g, bf16* l) {
    __builtin_amdgcn_global_load_lds(
        (const __attribute__((address_space(1))) void*)g,
        (__attribute__((address_space(3))) void*)l,
        16, 0, 0);
}

// ---------------------------------------------------------------------------
// gether1: X = gether(H) + H  (coefficient 2 on center row). fp32 in, bf16 out
// grid (8*S, 2); XCD-bijective swizzle (neighbor rows L2-resident).
// ---------------------------------------------------------------------------
__global__ __launch_bounds__(256) void k_gether1(
    const float* __restrict__ H, const float* __restrict__ Asim,
    const float* __restrict__ Tsim, const float* __restrict__ Adj,
    bf16* __restrict__ X)
{
    __shared__ float adjs[S];
    __shared__ float ts[S];
    __shared__ float diagf[DIN];
    int bx = blockIdx.x;
    bx = (bx & 7) * (gridDim.x >> 3) + (bx >> 3);  // 768 % 8 == 0: bijective
    int b = bx / S, l = bx % S;
    int tid = threadIdx.x;
    long row0 = (long)(b * S + l) * S;
    if (tid < S) {
        adjs[tid] = Adj[(b * S + l) * S + tid];
        ts[tid]   = Tsim[b * S + tid];
    }
    for (int i = tid; i < DIN / 4; i += 256)
        *(f32x4*)&diagf[i * 4] = *(const f32x4*)&H[(row0 + l) * DIN + i * 4];
    float a_up = (l > 0)     ? Asim[b * S + l - 1] : 0.f;
    float a_dn = (l < S - 1) ? Asim[b * S + l + 1] : 0.f;
    long du = (l > 0)     ? -(long)S * DIN : 0;
    long dd = (l < S - 1) ?  (long)S * DIN : 0;
    __syncthreads();

    int lane = tid & 63, wv = tid >> 6;
    int k0 = blockIdx.y * (S / 2);
    for (int k = k0 + wv; k < k0 + S / 2; k += 4) {
        float tl = (k > 0)     ? ts[k - 1] : 0.f;
        float tr = (k < S - 1) ? ts[k + 1] : 0.f;
        long  dl = (k > 0)     ? -(long)DIN : 0;
        long  dr = (k < S - 1) ?  (long)DIN : 0;
        float aj = adjs[k];
        const float* hrow = H + (row0 + k) * DIN;
        bf16* xrow = X + (row0 + k) * DIN;
#pragma unroll
        for (int c = 0; c < 3; ++c) {
            int col = (lane + c * 64) * 4;
            const float* hc = hrow + col;
            f32x4 vc = *(const f32x4*)hc;
            f32x4 vl = *(const f32x4*)(hc + dl);
            f32x4 vr = *(const f32x4*)(hc + dr);
            f32x4 vu = *(const f32x4*)(hc + du);
            f32x4 vd = *(const f32x4*)(hc + dd);
            bf16x4 o;
#pragma unroll
            for (int j = 0; j < 4; ++j) {
                float v = 2.f * vc[j] + aj * diagf[col + j]
                        + tl * vl[j] + tr * vr[j]
                        + a_up * vu[j] + a_dn * vd[j];
                o[j] = (bf16)v;
            }
            *(bf16x4*)&xrow[col] = o;
        }
    }
}

// ---------------------------------------------------------------------------
// gether2: sources are h1 = relu(g1 * y * invr) reconstructed on the fly.
// grid (8*S, 2); same XCD swizzle.
// ---------------------------------------------------------------------------
__global__ __launch_bounds__(256) void k_gether2(
    const bf16* __restrict__ Y, const float* __restrict__ INV,
    const float* __restrict__ G1, const float* __restrict__ Asim,
    const float* __restrict__ Tsim, const float* __restrict__ Adj,
    bf16* __restrict__ X)
{
    __shared__ float adjs[S];
    __shared__ float ts[S];
    __shared__ float diagf[DIN];
    __shared__ float g1s[DIN];
    int bx = blockIdx.x;
    bx = (bx & 7) * (gridDim.x >> 3) + (bx >> 3);
    int b = bx / S, l = bx % S;
    int tid = threadIdx.x;
    long row0 = (long)(b * S + l) * S;
    for (int i = tid; i < DIN; i += 256) g1s[i] = G1[i];
    __syncthreads();
    if (tid < S) {
        adjs[tid] = Adj[(b * S + l) * S + tid];
        ts[tid]   = Tsim[b * S + tid];
        float iv = INV[row0 + l];
        bf16x8 yv = *(const bf16x8*)&Y[(row0 + l) * DIN + tid * 8];
#pragma unroll
        for (int j = 0; j < 8; ++j) {
            float v = g1s[tid * 8 + j] * (float)yv[j] * iv;
            diagf[tid * 8 + j] = v > 0.f ? v : 0.f;
        }
    }
    float a_up = (l > 0)     ? Asim[b * S + l - 1] : 0.f;
    float a_dn = (l < S - 1) ? Asim[b * S + l + 1] : 0.f;
    long du = (l > 0)     ? -(long)S * DIN : 0;
    long dd = (l < S - 1) ?  (long)S * DIN : 0;
    int ou = (l > 0) ? -S : 0;
    int od = (l < S - 1) ? S : 0;
    __syncthreads();

    int lane = tid & 63, wv = tid >> 6;
    int k0 = blockIdx.y * (S / 2);
    for (int k = k0 + wv; k < k0 + S / 2; k += 4) {
        float tl = (k > 0)     ? ts[k - 1] : 0.f;
        float tr = (k < S - 1) ? ts[k + 1] : 0.f;
        int   ol = (k > 0)     ? -1 : 0;
        int   orr = (k < S - 1) ? 1 : 0;
        float aj = adjs[k];
        float ivc = INV[row0 + k];
        float ivl = INV[row0 + k + ol];
        float ivr = INV[row0 + k + orr];
        float ivu = INV[row0 + k + ou];
        float ivd = INV[row0 + k + od];
        const bf16* yrow = Y + (row0 + k) * DIN;
        bf16* xrow = X + (row0 + k) * DIN;
#pragma unroll
        for (int c = 0; c < 3; ++c) {
            int col = (lane + c * 64) * 4;
            const bf16* yc = yrow + col;
            bf16x4 vc = *(const bf16x4*)yc;
            bf16x4 vl = *(const bf16x4*)(yc + (long)ol * DIN);
            bf16x4 vr = *(const bf16x4*)(yc + (long)orr * DIN);
            bf16x4 vu = *(const bf16x4*)(yc + du);
            bf16x4 vd = *(const bf16x4*)(yc + dd);
            bf16x4 o;
#pragma unroll
            for (int j = 0; j < 4; ++j) {
                float g = g1s[col + j];
                float hc_ = g * (float)vc[j] * ivc; hc_ = hc_ > 0.f ? hc_ : 0.f;
                float hl_ = g * (float)vl[j] * ivl; hl_ = hl_ > 0.f ? hl_ : 0.f;
                float hr_ = g * (float)vr[j] * ivr; hr_ = hr_ > 0.f ? hr_ : 0.f;
                float hu_ = g * (float)vu[j] * ivu; hu_ = hu_ > 0.f ? hu_ : 0.f;
                float hd_ = g * (float)vd[j] * ivd; hd_ = hd_ > 0.f ? hd_ : 0.f;
                float v = 2.f * hc_ + aj * diagf[col + j]
                        + tl * hl_ + tr * hr_ + a_up * hu_ + a_dn * hd_;
                o[j] = (bf16)v;
            }
            *(bf16x4*)&xrow[col] = o;
        }
    }
}

// ---------------------------------------------------------------------------
// GEMM1: Y1[M x 768] = X @ W1T^T + b1 (bf16), ssq atomics.
// 128x128 tile, XOR swizzle, XCD-bijective block order (FETCH 345->77MB, r1).
// THIS ROUND: 3-buffer / 2-deep prefetch, ONE raw s_barrier per K-step,
// counted s_waitcnt vmcnt(4) (never 0 in the loop) -- T4. The old
// __syncthreads drained vmcnt(0) every step with ~1 iteration of compute to
// cover an L2 round trip; now stage t+1 stays in flight across the barrier.
// Safety: buf (t+2)%3 == buf (t-1)%3 was consumed by iter t-1's MFMAs (lgkm
// waits precede them), and every wave is past that point once it crosses
// iter t's barrier, so re-staging it cannot race the reads.
// ---------------------------------------------------------------------------
__global__ __launch_bounds__(256) void k_gemm1(
    const bf16* __restrict__ Xm, const bf16* __restrict__ WT,
    const float* __restrict__ bias, bf16* __restrict__ Y,
    float* __restrict__ ssq)
{
    constexpr int K = 768, N = 768;
    constexpr int NT = K / 32;  // 24
    __shared__ __align__(16) bf16 As[3][128 * 32];
    __shared__ __align__(16) bf16 Bs[3][128 * 32];
    int t = threadIdx.x;
    int wg = blockIdx.x;
    wg = (wg & 7) * (gridDim.x >> 3) + (wg >> 3);  // 3456 % 8 == 0: bijective
    int colBase = (wg % 6) * 128;                  // col fastest within XCD
    int rowBase = (wg / 6) * 128;
    int lane = t & 63, w = t >> 6;
    int quad = lane >> 4, l16 = lane & 15;
    int wr = w >> 1, wc = w & 1;

    floatx4 acc[4][4];
#pragma unroll
    for (int i = 0; i < 4; ++i)
#pragma unroll
        for (int j = 0; j < 4; ++j) acc[i][j] = (floatx4)0.f;

    int chunk = (t & 3) ^ ((t >> 3) & 3);
    const bf16* gA = Xm + (size_t)(rowBase + (t >> 2)) * K + chunk * 8;
    const bf16* gB = WT + (size_t)(colBase + (t >> 2)) * K + chunk * 8;
    int l8 = t * 8;

    auto stage = [&](int buf, int kk) {
        async16(gA + kk, &As[buf][l8]);
        async16(gA + kk + 64 * K, &As[buf][l8 + 2048]);
        async16(gB + kk, &Bs[buf][l8]);
        async16(gB + kk + 64 * K, &Bs[buf][l8 + 2048]);
    };

    stage(0, 0);
    stage(1, 32);
    for (int tt = 0; tt < NT; ++tt) {
        if (tt + 1 < NT) asm volatile("s_waitcnt vmcnt(4)" ::: "memory");
        else             asm volatile("s_waitcnt vmcnt(0)" ::: "memory");
        __builtin_amdgcn_s_barrier();
        int cur = tt % 3;
        bf16x8 af[4], bfr[4];
#pragma unroll
        for (int i = 0; i < 4; ++i) {
            int ra = wr * 64 + i * 16 + l16;
            af[i] = *(const bf16x8*)&As[cur][ra * 32 + (quad ^ ((ra >> 1) & 3)) * 8];
        }
#pragma unroll
        for (int j = 0; j < 4; ++j) {
            int rb = wc * 64 + j * 16 + l16;
            bfr[j] = *(const bf16x8*)&Bs[cur][rb * 32 + (quad ^ ((rb >> 1) & 3)) * 8];
        }
        if (tt + 2 < NT) stage((tt + 2) % 3, (tt + 2) * 32);
#pragma unroll
        for (int i = 0; i < 4; ++i)
#pragma unroll
            for (int j = 0; j < 4; ++j)
                acc[i][j] = __builtin_amdgcn_mfma_f32_16x16x32_bf16(
                    af[i], bfr[j], acc[i][j], 0, 0, 0);
    }

    float bv[4];
#pragma unroll
    for (int j = 0; j < 4; ++j)
        bv[j] = bias[colBase + wc * 64 + j * 16 + l16];
#pragma unroll
    for (int i = 0; i < 4; ++i) {
#pragma unroll
        for (int r = 0; r < 4; ++r) {
            int row = rowBase + wr * 64 + i * 16 + quad * 4 + r;
            bf16* yp = Y + (size_t)row * N + colBase + wc * 64 + l16;
            float s = 0.f;
#pragma unroll
            for (int j = 0; j < 4; ++j) {
                float v = acc[i][j][r] + bv[j];
                s += v * v;
                yp[j * 16] = (bf16)v;
            }
            s += __shfl_xor(s, 1);
            s += __shfl_xor(s, 2);
            s += __shfl_xor(s, 4);
            s += __shfl_xor(s, 8);
            if (l16 == 0) atomicAdd(&ssq[row], s);
        }
    }
}

// ---------------------------------------------------------------------------
// GEMM2 fused: out[M x 256] = relu(g2 * t5norm(X2 @ W2T^T + b2)) directly.
// Block covers 128 rows x ALL 256 cols; same T4 upgrade (3 buf, vmcnt(6)).
// LDS 72KB -> 2 blk/CU (unchanged vs before).
// ---------------------------------------------------------------------------
__global__ __launch_bounds__(256, 2) void k_gemm2f(
    const bf16* __restrict__ Xm, const bf16* __restrict__ WT,
    const float* __restrict__ bias, const float* __restrict__ G2,
    float* __restrict__ out)
{
    constexpr int K = 768, N = 256;
    constexpr int NT = K / 32;  // 24
    __shared__ __align__(16) bf16 As[3][128 * 32];
    __shared__ __align__(16) bf16 Bs[3][256 * 32];
    __shared__ float ssqs[2][128];
    int t = threadIdx.x;
    int rowBase = blockIdx.x * 128;
    int lane = t & 63, w = t >> 6;
    int quad = lane >> 4, l16 = lane & 15;
    int wr = w >> 1, wc = w & 1;

    floatx4 acc[4][8];
#pragma unroll
    for (int i = 0; i < 4; ++i)
#pragma unroll
        for (int j = 0; j < 8; ++j) acc[i][j] = (floatx4)0.f;

    int chunk = (t & 3) ^ ((t >> 3) & 3);
    const bf16* gA = Xm + (size_t)(rowBase + (t >> 2)) * K + chunk * 8;
    const bf16* gB = WT + (size_t)(t >> 2) * K + chunk * 8;
    int l8 = t * 8;

    auto stage = [&](int buf, int kk) {
        async16(gA + kk, &As[buf][l8]);
        async16(gA + kk + 64 * K, &As[buf][l8 + 2048]);
        async16(gB + kk, &Bs[buf][l8]);
        async16(gB + kk + 64 * K, &Bs[buf][l8 + 2048]);
        async16(gB + kk + 128 * K, &Bs[buf][l8 + 4096]);
        async16(gB + kk + 192 * K, &Bs[buf][l8 + 6144]);
    };

    stage(0, 0);
    stage(1, 32);
    for (int tt = 0; tt < NT; ++tt) {
        if (tt + 1 < NT) asm volatile("s_waitcnt vmcnt(6)" ::: "memory");
        else             asm volatile("s_waitcnt vmcnt(0)" ::: "memory");
        __builtin_amdgcn_s_barrier();
        int cur = tt % 3;
        bf16x8 af[4], bfr[8];
#pragma unroll
        for (int i = 0; i < 4; ++i) {
            int ra = wr * 64 + i * 16 + l16;
            af[i] = *(const bf16x8*)&As[cur][ra * 32 + (quad ^ ((ra >> 1) & 3)) * 8];
        }
#pragma unroll
        for (int j = 0; j < 8; ++j) {
            int rb = wc * 128 + j * 16 + l16;
            bfr[j] = *(const bf16x8*)&Bs[cur][rb * 32 + (quad ^ ((rb >> 1) & 3)) * 8];
        }
        if (tt + 2 < NT) stage((tt + 2) % 3, (tt + 2) * 32);
#pragma unroll
        for (int i = 0; i < 4; ++i)
#pragma unroll
            for (int j = 0; j < 8; ++j)
                acc[i][j] = __builtin_amdgcn_mfma_f32_16x16x32_bf16(
                    af[i], bfr[j], acc[i][j], 0, 0, 0);
    }

    float bv[8], gv[8];
#pragma unroll
    for (int j = 0; j < 8; ++j) {
        int col = wc * 128 + j * 16 + l16;
        bv[j] = bias[col];
        gv[j] = G2[col];
    }
    // per-row sum of squares -> LDS (each (wc, local row) slot written once)
#pragma unroll
    for (int i = 0; i < 4; ++i) {
#pragma unroll
        for (int r = 0; r < 4; ++r) {
            float s = 0.f;
#pragma unroll
            for (int j = 0; j < 8; ++j) {
                float v = acc[i][j][r] + bv[j];
                s += v * v;
            }
            s += __shfl_xor(s, 1);
            s += __shfl_xor(s, 2);
            s += __shfl_xor(s, 4);
            s += __shfl_xor(s, 8);
            if (l16 == 0)
                ssqs[wc][wr * 64 + i * 16 + quad * 4 + r] = s;
        }
    }
    __syncthreads();
#pragma unroll
    for (int i = 0; i < 4; ++i) {
#pragma unroll
        for (int r = 0; r < 4; ++r) {
            int lr = wr * 64 + i * 16 + quad * 4 + r;
            float inv = rsqrtf((ssqs[0][lr] + ssqs[1][lr]) * (1.f / N) + 1e-12f);
            float* op = out + (size_t)(rowBase + lr) * N + wc * 128 + l16;
#pragma unroll
            for (int j = 0; j < 8; ++j) {
                float v = (acc[i][j][r] + bv[j]) * gv[j] * inv;
                op[j * 16] = v > 0.f ? v : 0.f;
            }
        }
    }
}

// ---------------------------------------------------------------------------
__global__ __launch_bounds__(256) void k_invr(float* ssq, int n, float invD)
{
    int i = blockIdx.x * 256 + threadIdx.x;
    if (i < n) ssq[i] = rsqrtf(ssq[i] * invD + 1e-12f);
}

// tiled transpose + cast: in fp32 [R][C] -> out bf16 [C][R]; grid (C/32, R/32)
__global__ __launch_bounds__(256) void k_castT(
    const float* __restrict__ in, bf16* __restrict__ out, int R, int C)
{
    __shared__ float tile[32][33];
    int lx = threadIdx.x & 31, ly = threadIdx.x >> 5;
    int c0 = blockIdx.x * 32, r0 = blockIdx.y * 32;
#pragma unroll
    for (int k = 0; k < 4; ++k)
        tile[ly + 8 * k][lx] = in[(size_t)(r0 + ly + 8 * k) * C + c0 + lx];
    __syncthreads();
#pragma unroll
    for (int k = 0; k < 4; ++k)
        out[(size_t)(c0 + ly + 8 * k) * R + r0 + lx] = (bf16)tile[lx][ly + 8 * k];
}

// ---------------------------------------------------------------------------
extern "C" void kernel_launch(void* const* d_in, const int* in_sizes, int n_in,
                              void* d_out, int out_size, void* d_ws, size_t ws_size,
                              hipStream_t stream)
{
    const float* table = (const float*)d_in[0];
    const float* asim  = (const float*)d_in[1];
    const float* tsim  = (const float*)d_in[2];
    const float* adj   = (const float*)d_in[3];
    const float* W1    = (const float*)d_in[4];
    const float* b1    = (const float*)d_in[5];
    const float* g1    = (const float*)d_in[6];
    const float* W2    = (const float*)d_in[7];
    const float* b2    = (const float*)d_in[8];
    const float* g2    = (const float*)d_in[9];
    float* out = (float*)d_out;

    char* ws = (char*)d_ws;
    const size_t SZ_X = (size_t)MROWS * DIN * 2;          // 113246208 bytes
    bf16*  X    = (bf16*)ws;                               // [M,768] bf16
    bf16*  Y1   = (bf16*)(ws + SZ_X);                      // [M,768] bf16
    bf16*  W1T  = (bf16*)(ws + 2 * SZ_X);
    bf16*  W2T  = (bf16*)(ws + 2 * SZ_X + 1179648);
    float* ssq1 = (float*)(ws + 2 * SZ_X + 1179648 + 393216);

    hipMemsetAsync(ssq1, 0, (size_t)MROWS * 4, stream);
    k_castT<<<dim3(DIN / 32, DIN / 32), 256, 0, stream>>>(W1, W1T, DIN, DIN);
    k_castT<<<dim3(DOUT / 32, DIN / 32), 256, 0, stream>>>(W2, W2T, DIN, DOUT);

    k_gether1<<<dim3(8 * S, 2), 256, 0, stream>>>(table, asim, tsim, adj, X);
    k_gemm1<<<dim3((DIN / 128) * (MROWS / 128)), 256, 0, stream>>>(X, W1T, b1, Y1, ssq1);
    k_invr<<<MROWS / 256, 256, 0, stream>>>(ssq1, MROWS, 1.f / DIN);
    k_gether2<<<dim3(8 * S, 2), 256, 0, stream>>>(Y1, ssq1, g1, asim, tsim, adj, X);
    k_gemm2f<<<MROWS / 128, 256, 0, stream>>>(X, W2T, b2, g2, out);
}